// Round 1
// baseline (635.572 us; speedup 1.0000x reference)
//
#include <hip/hip_runtime.h>

namespace {

struct V3 { float x, y, z; };

__device__ inline V3 v3(float x, float y, float z) { return {x, y, z}; }
__device__ inline V3 vadd(V3 a, V3 b) { return {a.x + b.x, a.y + b.y, a.z + b.z}; }
__device__ inline V3 vsub(V3 a, V3 b) { return {a.x - b.x, a.y - b.y, a.z - b.z}; }
__device__ inline V3 vmul(float s, V3 a) { return {s * a.x, s * a.y, s * a.z}; }
__device__ inline V3 vneg(V3 a) { return {-a.x, -a.y, -a.z}; }

__device__ inline void store_frame(float4* o, V3 c0, V3 c1, V3 c2, V3 c3) {
    o[0] = make_float4(c0.x, c1.x, c2.x, c3.x);
    o[1] = make_float4(c0.y, c1.y, c2.y, c3.y);
    o[2] = make_float4(c0.z, c1.z, c2.z, c3.z);
    o[3] = make_float4(0.f, 0.f, 0.f, 1.f);
}

} // namespace

__global__ __launch_bounds__(256) void fk_chain_kernel(const float* __restrict__ q,
                                                       float4* __restrict__ out,
                                                       int n)
{
    int i = blockIdx.x * blockDim.x + threadIdx.x;
    if (i >= n) return;

    const float* qi = q + (size_t)i * 7;
    const float HPI = 1.57079632679489662f;

    float qv[7];
    #pragma unroll
    for (int k = 0; k < 7; ++k) qv[k] = qi[k];

    float c[7], s[7];
    __sincosf(qv[0], &s[0], &c[0]);
    __sincosf(qv[1], &s[1], &c[1]);
    __sincosf(qv[2] - HPI, &s[2], &c[2]);
    __sincosf(qv[3], &s[3], &c[3]);
    __sincosf(qv[4], &s[4], &c[4]);
    __sincosf(qv[5] + HPI, &s[5], &c[5]);
    __sincosf(qv[6] - HPI, &s[6], &c[6]);

    float4* o = out + (size_t)i * 32;  // 32 float4 = 128 floats per element

    // frame 0 = m0 (columns, bottom row implicit (0,0,0,1))
    V3 f0 = v3(c[0], s[0], 0.f);
    V3 f1 = v3(-s[0], c[0], 0.f);
    V3 f2 = v3(0.f, 0.f, 1.f);
    V3 f3 = v3(0.f, 0.f, 0.f);
    store_frame(o, f0, f1, f2, f3); o += 4;

    // "type A" joint (m1, m3, m5, m6):
    //   cols: c0'=(c,0,s,0) c1'=(-s,0,c,0) c2'=(0,-1,0,0) c3'=(0,0,0,1)
    //   => newf0 = c*f0 + s*f2 ; newf1 = c*f2 - s*f0 ; newf2 = -f1 ; f3 same
    #define TYPE_A(cc, ss)                              \
        {                                               \
            V3 t0 = vadd(vmul((cc), f0), vmul((ss), f2)); \
            V3 t1 = vsub(vmul((cc), f2), vmul((ss), f0)); \
            V3 t2 = vneg(f1);                           \
            f0 = t0; f1 = t1; f2 = t2;                  \
        }

    // m1
    TYPE_A(c[1], s[1]);
    store_frame(o, f0, f1, f2, f3); o += 4;

    // m2: cols c0'=(c,0,-s,0) c1'=(-s,0,-c,0) c2'=(0,1,0,0) c3'=(0,0.4,0,1)
    {
        V3 t0 = vsub(vmul(c[2], f0), vmul(s[2], f2));
        V3 t1 = vneg(vadd(vmul(s[2], f0), vmul(c[2], f2)));
        V3 t2 = f1;
        f3 = vadd(vmul(0.4f, f1), f3);
        f0 = t0; f1 = t1; f2 = t2;
    }
    store_frame(o, f0, f1, f2, f3); o += 4;

    // m3
    TYPE_A(c[3], s[3]);
    store_frame(o, f0, f1, f2, f3); o += 4;

    // m4: cols c0'=(-c,0,s,0) c1'=(s,0,c,0) c2'=(0,1,0,0) c3'=(0,0.39,0,1)
    {
        V3 t0 = vsub(vmul(s[4], f2), vmul(c[4], f0));
        V3 t1 = vadd(vmul(s[4], f0), vmul(c[4], f2));
        V3 t2 = f1;
        f3 = vadd(vmul(0.39f, f1), f3);
        f0 = t0; f1 = t1; f2 = t2;
    }
    store_frame(o, f0, f1, f2, f3); o += 4;

    // m5
    TYPE_A(c[5], s[5]);
    store_frame(o, f0, f1, f2, f3); o += 4;

    // m6
    TYPE_A(c[6], s[6]);
    store_frame(o, f0, f1, f2, f3); o += 4;

    // m7: cols c0'=(-1,0,0,0) c1'=(0,0,1,0) c2'=(0,1,0,0) c3'=(0,0.118,0,1)
    {
        V3 t0 = vneg(f0);
        V3 t1 = f2;
        V3 t2 = f1;
        f3 = vadd(vmul(0.118f, f1), f3);
        f0 = t0; f1 = t1; f2 = t2;
    }
    store_frame(o, f0, f1, f2, f3);

    #undef TYPE_A
}

extern "C" void kernel_launch(void* const* d_in, const int* in_sizes, int n_in,
                              void* d_out, int out_size, void* d_ws, size_t ws_size,
                              hipStream_t stream) {
    const float* x = (const float*)d_in[0];
    float* out = (float*)d_out;
    int n = in_sizes[0] / 7;  // 2,000,000
    int block = 256;
    int grid = (n + block - 1) / block;
    fk_chain_kernel<<<grid, block, 0, stream>>>(x, (float4*)out, n);
}

// Round 2
// 211.641 us; speedup vs baseline: 3.0031x; 3.0031x over previous
//
#include <hip/hip_runtime.h>

namespace {

struct V3 { float x, y, z; };

__device__ inline V3 v3(float x, float y, float z) { return {x, y, z}; }
__device__ inline V3 vadd(V3 a, V3 b) { return {a.x + b.x, a.y + b.y, a.z + b.z}; }
__device__ inline V3 vsub(V3 a, V3 b) { return {a.x - b.x, a.y - b.y, a.z - b.z}; }
__device__ inline V3 vmul(float s, V3 a) { return {s * a.x, s * a.y, s * a.z}; }
__device__ inline V3 vneg(V3 a) { return {-a.x, -a.y, -a.z}; }

// Stage one frame (4 row-float4s) at p[0..3]: rows r=(c0[r],c1[r],c2[r],c3[r]), row3=(0,0,0,1)
__device__ inline void stage_frame(float4* p, V3 c0, V3 c1, V3 c2, V3 c3) {
    p[0] = make_float4(c0.x, c1.x, c2.x, c3.x);
    p[1] = make_float4(c0.y, c1.y, c2.y, c3.y);
    p[2] = make_float4(c0.z, c1.z, c2.z, c3.z);
    p[3] = make_float4(0.f, 0.f, 0.f, 1.f);
}

} // namespace

// Per-wave LDS staging: [64 lanes][9 float4] (8 payload + 1 pad to break bank stride)
#define LPAD 9

__global__ __launch_bounds__(256) void fk_chain_kernel(const float* __restrict__ q,
                                                       float4* __restrict__ out,
                                                       int n)
{
    __shared__ float4 lds[4 * 64 * LPAD];  // 36,864 B

    const int tid  = threadIdx.x;
    const int lane = tid & 63;
    const int wave = tid >> 6;
    const long long e0 = (long long)blockIdx.x * 256 + (long long)wave * 64; // wave's first element
    if (e0 >= n) return;  // whole wave out of range (uniform)
    const long long i = e0 + lane;
    const bool active = i < (long long)n;

    const float* qi = q + (active ? i : 0) * 7;
    const float HPI = 1.57079632679489662f;

    float qv[7];
    #pragma unroll
    for (int k = 0; k < 7; ++k) qv[k] = qi[k];

    float c[7], s[7];
    __sincosf(qv[0], &s[0], &c[0]);
    __sincosf(qv[1], &s[1], &c[1]);
    __sincosf(qv[2] - HPI, &s[2], &c[2]);
    __sincosf(qv[3], &s[3], &c[3]);
    __sincosf(qv[4], &s[4], &c[4]);
    __sincosf(qv[5] + HPI, &s[5], &c[5]);
    __sincosf(qv[6] - HPI, &s[6], &c[6]);

    float4* ldsW = lds + wave * (64 * LPAD);
    float4* myS  = ldsW + lane * LPAD;     // this lane's staging slot (8 float4)

    // copy-out lane mapping: flat idx = j*64 + lane; e = idx>>3, k = idx&7
    const int rk = lane & 7;
    const int re = lane >> 3;
    // global float4 address = (e0+e)*32 + p*8 + k  =  e0*32 + j*256 + re*32 + p*8 + rk
    float4* gb = out + e0 * 32 + (long long)re * 32 + rk;

    // ---- chain state (columns of current frame, bottom row implicit) ----
    V3 f0 = v3(c[0], s[0], 0.f);
    V3 f1 = v3(-s[0], c[0], 0.f);
    V3 f2 = v3(0.f, 0.f, 1.f);
    V3 f3 = v3(0.f, 0.f, 0.f);

    // "type A" joint (m1, m3, m5, m6)
    #define TYPE_A(cc, ss)                                 \
        {                                                  \
            V3 t0 = vadd(vmul((cc), f0), vmul((ss), f2));  \
            V3 t1 = vsub(vmul((cc), f2), vmul((ss), f0));  \
            V3 t2 = vneg(f1);                              \
            f0 = t0; f1 = t1; f2 = t2;                     \
        }

    #define FLUSH(p)                                                      \
        {                                                                 \
            _Pragma("unroll")                                             \
            for (int j = 0; j < 8; ++j) {                                 \
                int e = j * 8 + re;                                       \
                float4 v = ldsW[e * LPAD + rk];                           \
                if (e0 + e < (long long)n) gb[(long long)j * 256 + (p) * 8] = v; \
            }                                                             \
        }

    // ---- phase 0: frames 0,1 ----
    stage_frame(myS + 0, f0, f1, f2, f3);
    TYPE_A(c[1], s[1]);
    stage_frame(myS + 4, f0, f1, f2, f3);
    FLUSH(0);

    // ---- phase 1: frames 2,3 ----
    // m2: newf0 = c*f0 - s*f2; newf1 = -(s*f0 + c*f2); newf2 = f1; f3 += 0.4*f1
    {
        V3 t0 = vsub(vmul(c[2], f0), vmul(s[2], f2));
        V3 t1 = vneg(vadd(vmul(s[2], f0), vmul(c[2], f2)));
        V3 t2 = f1;
        f3 = vadd(vmul(0.4f, f1), f3);
        f0 = t0; f1 = t1; f2 = t2;
    }
    stage_frame(myS + 0, f0, f1, f2, f3);
    TYPE_A(c[3], s[3]);
    stage_frame(myS + 4, f0, f1, f2, f3);
    FLUSH(1);

    // ---- phase 2: frames 4,5 ----
    // m4: newf0 = s*f2 - c*f0; newf1 = s*f0 + c*f2; newf2 = f1; f3 += 0.39*f1
    {
        V3 t0 = vsub(vmul(s[4], f2), vmul(c[4], f0));
        V3 t1 = vadd(vmul(s[4], f0), vmul(c[4], f2));
        V3 t2 = f1;
        f3 = vadd(vmul(0.39f, f1), f3);
        f0 = t0; f1 = t1; f2 = t2;
    }
    stage_frame(myS + 0, f0, f1, f2, f3);
    TYPE_A(c[5], s[5]);
    stage_frame(myS + 4, f0, f1, f2, f3);
    FLUSH(2);

    // ---- phase 3: frames 6,7 ----
    TYPE_A(c[6], s[6]);
    stage_frame(myS + 0, f0, f1, f2, f3);
    // m7: newf0 = -f0; newf1 = f2; newf2 = f1; f3 += 0.118*f1
    {
        V3 t0 = vneg(f0);
        V3 t1 = f2;
        V3 t2 = f1;
        f3 = vadd(vmul(0.118f, f1), f3);
        f0 = t0; f1 = t1; f2 = t2;
    }
    stage_frame(myS + 4, f0, f1, f2, f3);
    FLUSH(3);

    #undef TYPE_A
    #undef FLUSH
}

extern "C" void kernel_launch(void* const* d_in, const int* in_sizes, int n_in,
                              void* d_out, int out_size, void* d_ws, size_t ws_size,
                              hipStream_t stream) {
    const float* x = (const float*)d_in[0];
    float* out = (float*)d_out;
    int n = in_sizes[0] / 7;  // 2,000,000
    int block = 256;
    int grid = (n + block - 1) / block;
    fk_chain_kernel<<<grid, block, 0, stream>>>(x, (float4*)out, n);
}

// Round 3
// 192.814 us; speedup vs baseline: 3.2963x; 1.0976x over previous
//
#include <hip/hip_runtime.h>

namespace {

struct V3 { float x, y, z; };

__device__ inline V3 v3(float x, float y, float z) { return {x, y, z}; }
__device__ inline V3 vadd(V3 a, V3 b) { return {a.x + b.x, a.y + b.y, a.z + b.z}; }
__device__ inline V3 vsub(V3 a, V3 b) { return {a.x - b.x, a.y - b.y, a.z - b.z}; }
__device__ inline V3 vmul(float s, V3 a) { return {s * a.x, s * a.y, s * a.z}; }
__device__ inline V3 vneg(V3 a) { return {-a.x, -a.y, -a.z}; }

// Stage one frame (4 row-float4s): rows r = (c0[r], c1[r], c2[r], c3[r]); row3 = (0,0,0,1)
__device__ inline void stage_frame(float4* p, V3 c0, V3 c1, V3 c2, V3 c3) {
    p[0] = make_float4(c0.x, c1.x, c2.x, c3.x);
    p[1] = make_float4(c0.y, c1.y, c2.y, c3.y);
    p[2] = make_float4(c0.z, c1.z, c2.z, c3.z);
    p[3] = make_float4(0.f, 0.f, 0.f, 1.f);
}

} // namespace

// Per-lane LDS stride: 32 payload float4 (full 8 frames) + 1 pad
// (pad => lane stride 132 dwords == 4 mod 32 => same bank walk as contiguous)
#define LSTRIDE 33

__global__ __launch_bounds__(64) void fk_chain_kernel(const float* __restrict__ q,
                                                      float4* __restrict__ out,
                                                      int n)
{
    __shared__ float4 lds[64 * LSTRIDE];  // 33,792 B -> 4 blocks/CU

    const int lane = threadIdx.x;                       // block == 1 wave
    const long long e0 = (long long)blockIdx.x * 64;    // wave's first element
    const long long i = e0 + lane;
    const bool active = i < (long long)n;

    const float* qi = q + (active ? i : (long long)(n - 1)) * 7;
    const float HPI = 1.57079632679489662f;

    float qv[7];
    #pragma unroll
    for (int k = 0; k < 7; ++k) qv[k] = qi[k];

    float c[7], s[7];
    __sincosf(qv[0], &s[0], &c[0]);
    __sincosf(qv[1], &s[1], &c[1]);
    __sincosf(qv[2] - HPI, &s[2], &c[2]);
    __sincosf(qv[3], &s[3], &c[3]);
    __sincosf(qv[4], &s[4], &c[4]);
    __sincosf(qv[5] + HPI, &s[5], &c[5]);
    __sincosf(qv[6] - HPI, &s[6], &c[6]);

    float4* myS = lds + lane * LSTRIDE;  // this lane's 32-float4 staging slot

    // ---- chain state (columns of current frame; bottom row implicit) ----
    V3 f0 = v3(c[0], s[0], 0.f);
    V3 f1 = v3(-s[0], c[0], 0.f);
    V3 f2 = v3(0.f, 0.f, 1.f);
    V3 f3 = v3(0.f, 0.f, 0.f);

    // "type A" joint (m1, m3, m5, m6)
    #define TYPE_A(cc, ss)                                 \
        {                                                  \
            V3 t0 = vadd(vmul((cc), f0), vmul((ss), f2));  \
            V3 t1 = vsub(vmul((cc), f2), vmul((ss), f0));  \
            V3 t2 = vneg(f1);                              \
            f0 = t0; f1 = t1; f2 = t2;                     \
        }

    stage_frame(myS + 0, f0, f1, f2, f3);                  // frame 0 = m0

    TYPE_A(c[1], s[1]);                                    // m1
    stage_frame(myS + 4, f0, f1, f2, f3);

    // m2: f0' = c*f0 - s*f2; f1' = -(s*f0 + c*f2); f2' = f1; f3 += 0.4*f1
    {
        V3 t0 = vsub(vmul(c[2], f0), vmul(s[2], f2));
        V3 t1 = vneg(vadd(vmul(s[2], f0), vmul(c[2], f2)));
        V3 t2 = f1;
        f3 = vadd(vmul(0.4f, f1), f3);
        f0 = t0; f1 = t1; f2 = t2;
    }
    stage_frame(myS + 8, f0, f1, f2, f3);

    TYPE_A(c[3], s[3]);                                    // m3
    stage_frame(myS + 12, f0, f1, f2, f3);

    // m4: f0' = s*f2 - c*f0; f1' = s*f0 + c*f2; f2' = f1; f3 += 0.39*f1
    {
        V3 t0 = vsub(vmul(s[4], f2), vmul(c[4], f0));
        V3 t1 = vadd(vmul(s[4], f0), vmul(c[4], f2));
        V3 t2 = f1;
        f3 = vadd(vmul(0.39f, f1), f3);
        f0 = t0; f1 = t1; f2 = t2;
    }
    stage_frame(myS + 16, f0, f1, f2, f3);

    TYPE_A(c[5], s[5]);                                    // m5
    stage_frame(myS + 20, f0, f1, f2, f3);

    TYPE_A(c[6], s[6]);                                    // m6
    stage_frame(myS + 24, f0, f1, f2, f3);

    // m7: f0' = -f0; f1' = f2; f2' = f1; f3 += 0.118*f1
    {
        V3 t0 = vneg(f0);
        V3 t1 = f2;
        V3 t2 = f1;
        f3 = vadd(vmul(0.118f, f1), f3);
        f0 = t0; f1 = t1; f2 = t2;
    }
    stage_frame(myS + 28, f0, f1, f2, f3);

    #undef TYPE_A

    __syncthreads();  // 1 wave: ~free; guarantees ds_writes ordered before cross-lane reads

    // ---- flush: 32 fully-contiguous 1 KB wave stores (32 KB dense region) ----
    float4* gb = out + e0 * 32;
    if (e0 + 64 <= (long long)n) {
        #pragma unroll
        for (int j = 0; j < 32; ++j) {
            int flat = j * 64 + lane;                      // wave-region float4 index
            gb[flat] = lds[(flat >> 5) * LSTRIDE + (flat & 31)];
        }
    } else {
        #pragma unroll
        for (int j = 0; j < 32; ++j) {
            int flat = j * 64 + lane;
            if (e0 + (flat >> 5) < (long long)n)
                gb[flat] = lds[(flat >> 5) * LSTRIDE + (flat & 31)];
        }
    }
}

extern "C" void kernel_launch(void* const* d_in, const int* in_sizes, int n_in,
                              void* d_out, int out_size, void* d_ws, size_t ws_size,
                              hipStream_t stream) {
    const float* x = (const float*)d_in[0];
    float* out = (float*)d_out;
    int n = in_sizes[0] / 7;  // 2,000,000
    int grid = (n + 63) / 64; // one 64-lane wave per block
    fk_chain_kernel<<<grid, 64, 0, stream>>>(x, (float4*)out, n);
}